// Round 2
// baseline (184.347 us; speedup 1.0000x reference)
//
#include <hip/hip_runtime.h>
#include <hip/hip_cooperative_groups.h>

namespace cg = cooperative_groups;

#define M_VOX   100000
#define N_VOX   200000
#define K_VOL   27
#define C_IN    32
#define C_OUT   64

#define STG0        14                 // offsets in LDS stage 0
#define STG1        (K_VOL - STG0)     // 13 offsets in stage 1
#define BLK_THREADS 512                // 8 waves
#define VOX_PER_BLK 128
#define BURST       7                  // gather batch: loads issued before uses

// cooperative-launch geometry: 782 output tiles, grid-strided over 256 blocks
// (1 block/CU guaranteed residency even under conservative 64 KiB LDS
// accounting by the runtime's cooperative-capacity check — 391 blocks was
// rejected in r1 and silently produced zeros).
#define TILES        ((M_VOX + VOX_PER_BLK - 1) / VOX_PER_BLK)   // 782
#define GRID_BLOCKS  256
#define GRID_THREADS (GRID_BLOCKS * BLK_THREADS)                  // 131072

typedef __bf16 bf16x8 __attribute__((ext_vector_type(8)));
typedef float  floatx4 __attribute__((ext_vector_type(4)));

// ---- d_ws layout ----
// featsB : (N_VOX+1) rows x 32 bf16 (64 B/row), row N_VOX all-zero
// Bfrag  : 27 * 256 * 16 B bf16 weights in MFMA fragment order
#define FEATSB_BYTES  ((N_VOX + 1) * C_IN * 2)
#define BFRAG_OFF     FEATSB_BYTES
#define FEAT_CHUNKS   ((N_VOX + 1) * 4)
#define FEAT_BLOCKS   ((FEAT_CHUNKS + 255) / 256)

// ---------------- per-tile conv body (identical to r7 best kernel) ----------
// Wave = 16 voxels x 64 out-channels; B-frags staged in LDS (14+13 offsets).
// A-frag (16x16x32 bf16): A[m=lane&15][k=(lane>>4)*8+j]
// C/D: col=lane&15 (channel in tile), row=(lane>>4)*4+reg (voxel).
__device__ __forceinline__ void conv_tile(
    const int tileIdx,
    const __bf16* __restrict__ featsB,
    const bf16x8* __restrict__ BfragG,
    const int*    __restrict__ in_idx,
    const int*    __restrict__ mask,
    float*        __restrict__ out,
    bf16x8* ldsB)
{
    const int tid  = threadIdx.x;
    const int lane = tid & 63;
    const int wv   = tid >> 6;
    const int col  = lane & 15;
    const int quad = lane >> 4;

    const int m0 = tileIdx * VOX_PER_BLK + wv * 16;
    const bool active = (m0 < M_VOX);   // M_VOX%16==0: waves all-or-nothing

    // stage offsets 0..13 into LDS (all waves participate — barrier safety)
#pragma unroll
    for (int i = tid; i < STG0 * 256; i += BLK_THREADS) ldsB[i] = BfragG[i];

    // full index chain up front: 54 coalesced loads, mask fused -> zero row
    int mi[K_VOL];
    if (active) {
#pragma unroll
        for (int k = 0; k < K_VOL; ++k) {
            const int ix = in_idx[k * M_VOX + m0 + col];
            const int mk = mask[k * M_VOX + m0 + col];
            mi[k] = mk ? ix : N_VOX;
        }
    }
    __syncthreads();   // LDS stage 0 ready

    floatx4 acc0 = {0.f,0.f,0.f,0.f}, acc1 = {0.f,0.f,0.f,0.f};
    floatx4 acc2 = {0.f,0.f,0.f,0.f}, acc3 = {0.f,0.f,0.f,0.f};
    const bf16x8* lbase = ldsB + lane;
    const __bf16* fbase = featsB + quad * 8;

    bf16x8 A[BURST];

    if (active) {
        // ---- stage 0, batch 0: offsets 0..6 ----
#pragma unroll
        for (int j = 0; j < BURST; ++j)
            A[j] = *(const bf16x8*)(fbase + (size_t)mi[j] * C_IN);
#pragma unroll
        for (int j = 0; j < BURST; ++j) {
            const int k = j;
            bf16x8 b0 = lbase[k * 256 + 0 * 64];
            bf16x8 b1 = lbase[k * 256 + 1 * 64];
            bf16x8 b2 = lbase[k * 256 + 2 * 64];
            bf16x8 b3 = lbase[k * 256 + 3 * 64];
            acc0 = __builtin_amdgcn_mfma_f32_16x16x32_bf16(A[j], b0, acc0, 0, 0, 0);
            acc1 = __builtin_amdgcn_mfma_f32_16x16x32_bf16(A[j], b1, acc1, 0, 0, 0);
            acc2 = __builtin_amdgcn_mfma_f32_16x16x32_bf16(A[j], b2, acc2, 0, 0, 0);
            acc3 = __builtin_amdgcn_mfma_f32_16x16x32_bf16(A[j], b3, acc3, 0, 0, 0);
        }
        // ---- stage 0, batch 1: offsets 7..13 ----
#pragma unroll
        for (int j = 0; j < BURST; ++j)
            A[j] = *(const bf16x8*)(fbase + (size_t)mi[BURST + j] * C_IN);
#pragma unroll
        for (int j = 0; j < BURST; ++j) {
            const int k = BURST + j;
            bf16x8 b0 = lbase[k * 256 + 0 * 64];
            bf16x8 b1 = lbase[k * 256 + 1 * 64];
            bf16x8 b2 = lbase[k * 256 + 2 * 64];
            bf16x8 b3 = lbase[k * 256 + 3 * 64];
            acc0 = __builtin_amdgcn_mfma_f32_16x16x32_bf16(A[j], b0, acc0, 0, 0, 0);
            acc1 = __builtin_amdgcn_mfma_f32_16x16x32_bf16(A[j], b1, acc1, 0, 0, 0);
            acc2 = __builtin_amdgcn_mfma_f32_16x16x32_bf16(A[j], b2, acc2, 0, 0, 0);
            acc3 = __builtin_amdgcn_mfma_f32_16x16x32_bf16(A[j], b3, acc3, 0, 0, 0);
        }
    }

    // ---- restage LDS with offsets 14..26 ----
    __syncthreads();   // everyone done reading LDS stage 0
#pragma unroll
    for (int i = tid; i < STG1 * 256; i += BLK_THREADS)
        ldsB[i] = BfragG[STG0 * 256 + i];
    __syncthreads();   // LDS stage 1 ready

    if (active) {
        // ---- stage 1, batch 0: offsets 14..20 ----
#pragma unroll
        for (int j = 0; j < BURST; ++j)
            A[j] = *(const bf16x8*)(fbase + (size_t)mi[STG0 + j] * C_IN);
#pragma unroll
        for (int j = 0; j < BURST; ++j) {
            const int k = j;
            bf16x8 b0 = lbase[k * 256 + 0 * 64];
            bf16x8 b1 = lbase[k * 256 + 1 * 64];
            bf16x8 b2 = lbase[k * 256 + 2 * 64];
            bf16x8 b3 = lbase[k * 256 + 3 * 64];
            acc0 = __builtin_amdgcn_mfma_f32_16x16x32_bf16(A[j], b0, acc0, 0, 0, 0);
            acc1 = __builtin_amdgcn_mfma_f32_16x16x32_bf16(A[j], b1, acc1, 0, 0, 0);
            acc2 = __builtin_amdgcn_mfma_f32_16x16x32_bf16(A[j], b2, acc2, 0, 0, 0);
            acc3 = __builtin_amdgcn_mfma_f32_16x16x32_bf16(A[j], b3, acc3, 0, 0, 0);
        }
        // ---- stage 1, batch 1: offsets 21..26 (6 iters) ----
#pragma unroll
        for (int j = 0; j < STG1 - BURST; ++j)
            A[j] = *(const bf16x8*)(fbase + (size_t)mi[STG0 + BURST + j] * C_IN);
#pragma unroll
        for (int j = 0; j < STG1 - BURST; ++j) {
            const int k = BURST + j;
            bf16x8 b0 = lbase[k * 256 + 0 * 64];
            bf16x8 b1 = lbase[k * 256 + 1 * 64];
            bf16x8 b2 = lbase[k * 256 + 2 * 64];
            bf16x8 b3 = lbase[k * 256 + 3 * 64];
            acc0 = __builtin_amdgcn_mfma_f32_16x16x32_bf16(A[j], b0, acc0, 0, 0, 0);
            acc1 = __builtin_amdgcn_mfma_f32_16x16x32_bf16(A[j], b1, acc1, 0, 0, 0);
            acc2 = __builtin_amdgcn_mfma_f32_16x16x32_bf16(A[j], b2, acc2, 0, 0, 0);
            acc3 = __builtin_amdgcn_mfma_f32_16x16x32_bf16(A[j], b3, acc3, 0, 0, 0);
        }

        float* op = out + (size_t)(m0 + quad * 4) * C_OUT + col;
#pragma unroll
        for (int r = 0; r < 4; ++r) {
            op[r * C_OUT + 0]  = acc0[r];
            op[r * C_OUT + 16] = acc1[r];
            op[r * C_OUT + 32] = acc2[r];
            op[r * C_OUT + 48] = acc3[r];
        }
    }
}

// ---------------- fused kernel: prep (phase 1) + grid.sync + conv (phase 2) --
__global__ __launch_bounds__(BLK_THREADS, 4) void fused_all(
    const float* __restrict__ feats, const float* __restrict__ kernelw,
    const int*   __restrict__ in_idx, const int* __restrict__ mask,
    __bf16* __restrict__ featsB, bf16x8* __restrict__ BfragG,
    float*  __restrict__ out)
{
    __shared__ bf16x8 ldsB[STG0 * 256];   // 57,344 B

    const int tid  = threadIdx.x;
    const int gtid = blockIdx.x * BLK_THREADS + tid;

    // --- phase 1a: weight frags (first 27*256 = 6912 threads) ---
    // element j = kernel[k][((lane>>4)&3)*8 + j][tile*16 + (lane&15)]
    if (gtid < K_VOL * 256) {
        const int k    = gtid >> 8;
        const int t8   = gtid & 255;
        const int tile = t8 >> 6;
        const int col  = t8 & 15;
        const int quad = (t8 >> 4) & 3;
        const float* kp = kernelw + k * C_IN * C_OUT + quad * 8 * C_OUT + tile * 16 + col;
        bf16x8 b;
#pragma unroll
        for (int j = 0; j < 8; ++j) b[j] = (__bf16)kp[j * C_OUT];
        BfragG[gtid] = b;
    }

    // --- phase 1b: feats fp32 -> bf16 (+zero row), grid-stride, ~6 chunks/thr
    for (int c = gtid; c < FEAT_CHUNKS; c += GRID_THREADS) {
        bf16x8 v;
        if (c < N_VOX * 4) {
            floatx4 f0 = *(const floatx4*)(feats + (size_t)c * 8);
            floatx4 f1 = *(const floatx4*)(feats + (size_t)c * 8 + 4);
#pragma unroll
            for (int j = 0; j < 4; ++j) { v[j] = (__bf16)f0[j]; v[4 + j] = (__bf16)f1[j]; }
        } else {
#pragma unroll
            for (int j = 0; j < 8; ++j) v[j] = (__bf16)0.0f;
        }
        *(bf16x8*)(featsB + (size_t)c * 8) = v;
    }

    cg::this_grid().sync();   // featsB + BfragG ready everywhere

    // --- phase 2: grid-stride over the 782 output tiles (3-4 per block) ---
    for (int t = blockIdx.x; t < TILES; t += GRID_BLOCKS) {
        conv_tile(t, featsB, BfragG, in_idx, mask, out, ldsB);
        __syncthreads();   // all waves done reading LDS before next restage
    }
}

// ---------------- fallback path (if cooperative launch is rejected) ---------
__global__ __launch_bounds__(256) void prep_all(
    const float* __restrict__ feats, const float* __restrict__ kernelw,
    __bf16* __restrict__ featsB, bf16x8* __restrict__ Bfrag)
{
    if (blockIdx.x < FEAT_BLOCKS) {
        const int c = blockIdx.x * 256 + threadIdx.x;
        if (c >= FEAT_CHUNKS) return;
        bf16x8 v;
        if (c < N_VOX * 4) {
            floatx4 f0 = *(const floatx4*)(feats + (size_t)c * 8);
            floatx4 f1 = *(const floatx4*)(feats + (size_t)c * 8 + 4);
#pragma unroll
            for (int j = 0; j < 4; ++j) { v[j] = (__bf16)f0[j]; v[4 + j] = (__bf16)f1[j]; }
        } else {
#pragma unroll
            for (int j = 0; j < 8; ++j) v[j] = (__bf16)0.0f;
        }
        *(bf16x8*)(featsB + (size_t)c * 8) = v;
    } else {
        const int k    = blockIdx.x - FEAT_BLOCKS;
        const int tid  = threadIdx.x;
        const int tile = tid >> 6;
        const int col  = tid & 15;
        const int quad = (tid >> 4) & 3;
        const float* kp = kernelw + k * C_IN * C_OUT + quad * 8 * C_OUT + tile * 16 + col;
        bf16x8 b;
#pragma unroll
        for (int j = 0; j < 8; ++j) b[j] = (__bf16)kp[j * C_OUT];
        Bfrag[k * 256 + tid] = b;
    }
}

__global__ __launch_bounds__(BLK_THREADS) void conv_only(
    const __bf16* __restrict__ featsB,
    const bf16x8* __restrict__ BfragG,
    const int* __restrict__ in_idx,
    const int* __restrict__ mask,
    float* __restrict__ out)
{
    __shared__ bf16x8 ldsB[STG0 * 256];
    conv_tile(blockIdx.x, featsB, BfragG, in_idx, mask, out, ldsB);
}

extern "C" void kernel_launch(void* const* d_in, const int* in_sizes, int n_in,
                              void* d_out, int out_size, void* d_ws, size_t ws_size,
                              hipStream_t stream) {
    const float* feats   = (const float*)d_in[0];
    const float* kernelw = (const float*)d_in[1];
    const int*   in_idx  = (const int*)d_in[2];
    const int*   maskp   = (const int*)d_in[3];
    float*       out     = (float*)d_out;

    __bf16* featsB = (__bf16*)d_ws;
    bf16x8* BfragP = (bf16x8*)((char*)d_ws + BFRAG_OFF);

    void* args[] = { (void*)&feats, (void*)&kernelw, (void*)&in_idx, (void*)&maskp,
                     (void*)&featsB, (void*)&BfragP, (void*)&out };
    hipError_t e = hipLaunchCooperativeKernel((void*)fused_all, dim3(GRID_BLOCKS),
                                              dim3(BLK_THREADS), args, 0, stream);
    if (e != hipSuccess) {
        // cooperative launch rejected (capacity/capture) -> proven 2-kernel path
        prep_all<<<dim3(FEAT_BLOCKS + K_VOL), dim3(256), 0, stream>>>(
            feats, kernelw, featsB, BfragP);
        sparse_conv_fallback:
        conv_only<<<dim3(TILES), dim3(BLK_THREADS), 0, stream>>>(
            featsB, BfragP, in_idx, maskp, out);
    }
}

// Round 3
// 124.075 us; speedup vs baseline: 1.4858x; 1.4858x over previous
//
#include <hip/hip_runtime.h>

#define M_VOX   100000
#define N_VOX   200000
#define K_VOL   27
#define C_IN    32
#define C_OUT   64

#define NSTG        3                  // LDS stages
#define STG         9                  // offsets per stage (3*9 = 27)
#define BLK_THREADS 512                // 8 waves; 128 voxels per block
#define VOX_PER_BLK 128
#define BURST       5                  // gather batch (5+4 per stage)

typedef __bf16 bf16x8 __attribute__((ext_vector_type(8)));
typedef float  floatx4 __attribute__((ext_vector_type(4)));

// ---- d_ws layout ----
// featsB : (N_VOX+1) rows x 32 bf16 (64 B/row), row N_VOX all-zero
// Bfrag  : 27 * 256 * 16 B bf16 weights in MFMA fragment order
#define FEATSB_BYTES  ((N_VOX + 1) * C_IN * 2)
#define BFRAG_OFF     FEATSB_BYTES

// ---------- fused prep: feats fp32->bf16 (+zero row) | weights->frag ----------
#define FEAT_CHUNKS   ((N_VOX + 1) * 4)
#define FEAT_BLOCKS   ((FEAT_CHUNKS + 255) / 256)
__global__ __launch_bounds__(256) void prep_all(
    const float* __restrict__ feats, const float* __restrict__ kernelw,
    __bf16* __restrict__ featsB, bf16x8* __restrict__ Bfrag)
{
    if (blockIdx.x < FEAT_BLOCKS) {
        const int c = blockIdx.x * 256 + threadIdx.x;
        if (c >= FEAT_CHUNKS) return;
        bf16x8 v;
        if (c < N_VOX * 4) {
            floatx4 f0 = *(const floatx4*)(feats + c * 8);
            floatx4 f1 = *(const floatx4*)(feats + c * 8 + 4);
#pragma unroll
            for (int j = 0; j < 4; ++j) { v[j] = (__bf16)f0[j]; v[4 + j] = (__bf16)f1[j]; }
        } else {
#pragma unroll
            for (int j = 0; j < 8; ++j) v[j] = (__bf16)0.0f;
        }
        *(bf16x8*)(featsB + c * 8) = v;
    } else {
        // weight frag: block k, thread tid -> slot (tile=tid>>6, lane=tid&63)
        // element j = kernel[k][((lane>>4)&3)*8 + j][tile*16 + (lane&15)]
        const int k    = blockIdx.x - FEAT_BLOCKS;
        const int tid  = threadIdx.x;
        const int tile = tid >> 6;
        const int col  = tid & 15;
        const int quad = (tid >> 4) & 3;
        const float* kp = kernelw + k * C_IN * C_OUT + quad * 8 * C_OUT + tile * 16 + col;
        bf16x8 b;
#pragma unroll
        for (int j = 0; j < 8; ++j) b[j] = (__bf16)kp[j * C_OUT];
        Bfrag[k * 256 + tid] = b;
    }
}

// ---------- main ----------
// r9: occupancy experiment. Round-2 showed gather throughput is concurrency-
// sensitive (8 waves/CU -> 1601 GB/s, 16 -> 2404). This version cuts LDS to
// 3 stages x 9 offsets (36,864 B) -> 4 blocks/CU = 32 waves/CU, to test
// whether the L2/L3 random-line service has headroom past 16 waves/CU.
// Everything else identical to the 122 us round-0 kernel.
// Wave = 16 voxels x 64 out-channels; block = 512 thr = 8 waves.
// A-frag (16x16x32 bf16): A[m=lane&15][k=(lane>>4)*8+j]
// C/D: col=lane&15 (channel in tile), row=(lane>>4)*4+reg (voxel).
__global__ __launch_bounds__(BLK_THREADS) void sparse_conv_mfma(
    const __bf16* __restrict__ featsB,
    const bf16x8* __restrict__ BfragG,
    const int* __restrict__ in_idx,
    const int* __restrict__ mask,
    float* __restrict__ out)
{
    __shared__ bf16x8 ldsB[STG * 256];   // 36,864 B -> 4 blocks/CU

    const int tid  = threadIdx.x;
    const int lane = tid & 63;
    const int wv   = tid >> 6;
    const int col  = lane & 15;
    const int quad = lane >> 4;

    const int m0 = blockIdx.x * VOX_PER_BLK + wv * 16;
    const bool active = (m0 < M_VOX);   // M_VOX%16==0: waves all-or-nothing

    // stage offsets 0..8 into LDS (all waves participate — barrier safety)
#pragma unroll
    for (int i = tid; i < STG * 256; i += BLK_THREADS) ldsB[i] = BfragG[i];

    // full index chain up front: 54 coalesced loads, mask fused -> zero row
    int mi[K_VOL];
    if (active) {
#pragma unroll
        for (int k = 0; k < K_VOL; ++k) {
            const int ix = in_idx[k * M_VOX + m0 + col];
            const int mk = mask[k * M_VOX + m0 + col];
            mi[k] = mk ? ix : N_VOX;
        }
    }
    __syncthreads();   // LDS stage 0 ready

    floatx4 acc0 = {0.f,0.f,0.f,0.f}, acc1 = {0.f,0.f,0.f,0.f};
    floatx4 acc2 = {0.f,0.f,0.f,0.f}, acc3 = {0.f,0.f,0.f,0.f};
    const bf16x8* lbase = ldsB + lane;
    const __bf16* fbase = featsB + quad * 8;

    bf16x8 A[BURST];

#pragma unroll
    for (int s = 0; s < NSTG; ++s) {
        if (s) {
            __syncthreads();   // everyone done reading previous stage
#pragma unroll
            for (int i = tid; i < STG * 256; i += BLK_THREADS)
                ldsB[i] = BfragG[s * STG * 256 + i];
            __syncthreads();   // stage s ready
        }
        if (active) {
            // ---- batch 0: offsets 9s .. 9s+4 ----
#pragma unroll
            for (int j = 0; j < BURST; ++j)
                A[j] = *(const bf16x8*)(fbase + (size_t)mi[s * STG + j] * C_IN);
#pragma unroll
            for (int j = 0; j < BURST; ++j) {
                const int k = j;
                bf16x8 b0 = lbase[k * 256 + 0 * 64];
                bf16x8 b1 = lbase[k * 256 + 1 * 64];
                bf16x8 b2 = lbase[k * 256 + 2 * 64];
                bf16x8 b3 = lbase[k * 256 + 3 * 64];
                acc0 = __builtin_amdgcn_mfma_f32_16x16x32_bf16(A[j], b0, acc0, 0, 0, 0);
                acc1 = __builtin_amdgcn_mfma_f32_16x16x32_bf16(A[j], b1, acc1, 0, 0, 0);
                acc2 = __builtin_amdgcn_mfma_f32_16x16x32_bf16(A[j], b2, acc2, 0, 0, 0);
                acc3 = __builtin_amdgcn_mfma_f32_16x16x32_bf16(A[j], b3, acc3, 0, 0, 0);
            }
            // ---- batch 1: offsets 9s+5 .. 9s+8 ----
#pragma unroll
            for (int j = 0; j < STG - BURST; ++j)
                A[j] = *(const bf16x8*)(fbase + (size_t)mi[s * STG + BURST + j] * C_IN);
#pragma unroll
            for (int j = 0; j < STG - BURST; ++j) {
                const int k = BURST + j;
                bf16x8 b0 = lbase[k * 256 + 0 * 64];
                bf16x8 b1 = lbase[k * 256 + 1 * 64];
                bf16x8 b2 = lbase[k * 256 + 2 * 64];
                bf16x8 b3 = lbase[k * 256 + 3 * 64];
                acc0 = __builtin_amdgcn_mfma_f32_16x16x32_bf16(A[j], b0, acc0, 0, 0, 0);
                acc1 = __builtin_amdgcn_mfma_f32_16x16x32_bf16(A[j], b1, acc1, 0, 0, 0);
                acc2 = __builtin_amdgcn_mfma_f32_16x16x32_bf16(A[j], b2, acc2, 0, 0, 0);
                acc3 = __builtin_amdgcn_mfma_f32_16x16x32_bf16(A[j], b3, acc3, 0, 0, 0);
            }
        }
    }

    if (active) {
        float* op = out + (size_t)(m0 + quad * 4) * C_OUT + col;
#pragma unroll
        for (int r = 0; r < 4; ++r) {
            op[r * C_OUT + 0]  = acc0[r];
            op[r * C_OUT + 16] = acc1[r];
            op[r * C_OUT + 32] = acc2[r];
            op[r * C_OUT + 48] = acc3[r];
        }
    }
}

extern "C" void kernel_launch(void* const* d_in, const int* in_sizes, int n_in,
                              void* d_out, int out_size, void* d_ws, size_t ws_size,
                              hipStream_t stream) {
    const float* feats   = (const float*)d_in[0];
    const float* kernelw = (const float*)d_in[1];
    const int*   in_idx  = (const int*)d_in[2];
    const int*   maskp   = (const int*)d_in[3];
    float*       out     = (float*)d_out;

    __bf16* featsB = (__bf16*)d_ws;
    bf16x8* BfragP = (bf16x8*)((char*)d_ws + BFRAG_OFF);

    prep_all<<<dim3(FEAT_BLOCKS + K_VOL), dim3(256), 0, stream>>>(
        feats, kernelw, featsB, BfragP);

    const int blocks = (M_VOX + VOX_PER_BLK - 1) / VOX_PER_BLK;   // 782
    sparse_conv_mfma<<<dim3(blocks), dim3(BLK_THREADS), 0, stream>>>(
        featsB, BfragP, in_idx, maskp, out);
}

// Round 4
// 121.502 us; speedup vs baseline: 1.5172x; 1.0212x over previous
//
#include <hip/hip_runtime.h>

#define M_VOX   100000
#define N_VOX   200000
#define K_VOL   27
#define C_IN    32
#define C_OUT   64

#define STG0        14                 // offsets in LDS stage 0
#define STG1        (K_VOL - STG0)     // 13 offsets in stage 1
#define BLK_THREADS 512                // 8 waves; 128 voxels per block
#define VOX_PER_BLK 128
#define BURST       7                  // gather batch: loads issued before uses

typedef __bf16 bf16x8 __attribute__((ext_vector_type(8)));
typedef float  floatx4 __attribute__((ext_vector_type(4)));

// ---- d_ws layout ----
// featsB : (N_VOX+1) rows x 32 bf16 (64 B/row), row N_VOX all-zero
// Bfrag  : 27 * 256 * 16 B bf16 weights in MFMA fragment order
#define FEATSB_BYTES  ((N_VOX + 1) * C_IN * 2)
#define BFRAG_OFF     FEATSB_BYTES

// ---------- fused prep: feats fp32->bf16 (+zero row) | weights->frag ----------
#define FEAT_CHUNKS   ((N_VOX + 1) * 4)
#define FEAT_BLOCKS   ((FEAT_CHUNKS + 255) / 256)
__global__ __launch_bounds__(256) void prep_all(
    const float* __restrict__ feats, const float* __restrict__ kernelw,
    __bf16* __restrict__ featsB, bf16x8* __restrict__ Bfrag)
{
    if (blockIdx.x < FEAT_BLOCKS) {
        const int c = blockIdx.x * 256 + threadIdx.x;
        if (c >= FEAT_CHUNKS) return;
        bf16x8 v;
        if (c < N_VOX * 4) {
            floatx4 f0 = *(const floatx4*)(feats + c * 8);
            floatx4 f1 = *(const floatx4*)(feats + c * 8 + 4);
#pragma unroll
            for (int j = 0; j < 4; ++j) { v[j] = (__bf16)f0[j]; v[4 + j] = (__bf16)f1[j]; }
        } else {
#pragma unroll
            for (int j = 0; j < 8; ++j) v[j] = (__bf16)0.0f;
        }
        *(bf16x8*)(featsB + c * 8) = v;
    } else {
        // weight frag: block k, thread tid -> slot (tile=tid>>6, lane=tid&63)
        // element j = kernel[k][((lane>>4)&3)*8 + j][tile*16 + (lane&15)]
        const int k    = blockIdx.x - FEAT_BLOCKS;
        const int tid  = threadIdx.x;
        const int tile = tid >> 6;
        const int col  = tid & 15;
        const int quad = (tid >> 4) & 3;
        const float* kp = kernelw + k * C_IN * C_OUT + quad * 8 * C_OUT + tile * 16 + col;
        bf16x8 b;
#pragma unroll
        for (int j = 0; j < 8; ++j) b[j] = (__bf16)kp[j * C_OUT];
        Bfrag[k * 256 + tid] = b;
    }
}

// ---------- main ----------
// Best-known configuration (r7 / round-0, 122.1 us end-to-end, conv 42.4 us).
// Wave = 16 voxels x 64 out-channels; block = 512 thr = 8 waves; B-frags
// staged in LDS (14+13 offsets, 57,344 B) -> 2 blocks/CU = 16 waves/CU.
// Gathers issued in bursts of 7 (loads precede uses -> MLP 7/wave).
//
// Measured bound (rounds 0-3): scattered 64-B line service in the
// L2-miss/L3 path, ~2.05 TB/s effective (86 MB random row traffic / 42 us).
// Concurrency curve: 8 waves/CU -> 1601 GB/s, 16 -> 2404, 32 -> ~2400
// (saturated at 16). Insensitive to MFMA shape, gather MLP, occupancy past
// 16 waves/CU, and LDS-pipe load. fp8 rows (32 B) would halve traffic but
// predicted absmax ~0.078 > 0.045 threshold. This is the floor.
// A-frag (16x16x32 bf16): A[m=lane&15][k=(lane>>4)*8+j]
// C/D: col=lane&15 (channel in tile), row=(lane>>4)*4+reg (voxel).
__global__ __launch_bounds__(BLK_THREADS) void sparse_conv_mfma(
    const __bf16* __restrict__ featsB,
    const bf16x8* __restrict__ BfragG,
    const int* __restrict__ in_idx,
    const int* __restrict__ mask,
    float* __restrict__ out)
{
    __shared__ bf16x8 ldsB[STG0 * 256];   // 57,344 B

    const int tid  = threadIdx.x;
    const int lane = tid & 63;
    const int wv   = tid >> 6;
    const int col  = lane & 15;
    const int quad = lane >> 4;

    const int m0 = blockIdx.x * VOX_PER_BLK + wv * 16;
    const bool active = (m0 < M_VOX);   // M_VOX%16==0: waves all-or-nothing

    // stage offsets 0..13 into LDS (all waves participate — barrier safety)
#pragma unroll
    for (int i = tid; i < STG0 * 256; i += BLK_THREADS) ldsB[i] = BfragG[i];

    // full index chain up front: 54 coalesced loads, mask fused -> zero row
    int mi[K_VOL];
    if (active) {
#pragma unroll
        for (int k = 0; k < K_VOL; ++k) {
            const int ix = in_idx[k * M_VOX + m0 + col];
            const int mk = mask[k * M_VOX + m0 + col];
            mi[k] = mk ? ix : N_VOX;
        }
    }
    __syncthreads();   // LDS stage 0 ready

    floatx4 acc0 = {0.f,0.f,0.f,0.f}, acc1 = {0.f,0.f,0.f,0.f};
    floatx4 acc2 = {0.f,0.f,0.f,0.f}, acc3 = {0.f,0.f,0.f,0.f};
    const bf16x8* lbase = ldsB + lane;
    const __bf16* fbase = featsB + quad * 8;

    bf16x8 A[BURST];

    if (active) {
        // ---- stage 0, batch 0: offsets 0..6 ----
#pragma unroll
        for (int j = 0; j < BURST; ++j)
            A[j] = *(const bf16x8*)(fbase + (size_t)mi[j] * C_IN);
#pragma unroll
        for (int j = 0; j < BURST; ++j) {
            const int k = j;
            bf16x8 b0 = lbase[k * 256 + 0 * 64];
            bf16x8 b1 = lbase[k * 256 + 1 * 64];
            bf16x8 b2 = lbase[k * 256 + 2 * 64];
            bf16x8 b3 = lbase[k * 256 + 3 * 64];
            acc0 = __builtin_amdgcn_mfma_f32_16x16x32_bf16(A[j], b0, acc0, 0, 0, 0);
            acc1 = __builtin_amdgcn_mfma_f32_16x16x32_bf16(A[j], b1, acc1, 0, 0, 0);
            acc2 = __builtin_amdgcn_mfma_f32_16x16x32_bf16(A[j], b2, acc2, 0, 0, 0);
            acc3 = __builtin_amdgcn_mfma_f32_16x16x32_bf16(A[j], b3, acc3, 0, 0, 0);
        }
        // ---- stage 0, batch 1: offsets 7..13 ----
#pragma unroll
        for (int j = 0; j < BURST; ++j)
            A[j] = *(const bf16x8*)(fbase + (size_t)mi[BURST + j] * C_IN);
#pragma unroll
        for (int j = 0; j < BURST; ++j) {
            const int k = BURST + j;
            bf16x8 b0 = lbase[k * 256 + 0 * 64];
            bf16x8 b1 = lbase[k * 256 + 1 * 64];
            bf16x8 b2 = lbase[k * 256 + 2 * 64];
            bf16x8 b3 = lbase[k * 256 + 3 * 64];
            acc0 = __builtin_amdgcn_mfma_f32_16x16x32_bf16(A[j], b0, acc0, 0, 0, 0);
            acc1 = __builtin_amdgcn_mfma_f32_16x16x32_bf16(A[j], b1, acc1, 0, 0, 0);
            acc2 = __builtin_amdgcn_mfma_f32_16x16x32_bf16(A[j], b2, acc2, 0, 0, 0);
            acc3 = __builtin_amdgcn_mfma_f32_16x16x32_bf16(A[j], b3, acc3, 0, 0, 0);
        }
    }

    // ---- restage LDS with offsets 14..26 ----
    __syncthreads();   // everyone done reading LDS stage 0
#pragma unroll
    for (int i = tid; i < STG1 * 256; i += BLK_THREADS)
        ldsB[i] = BfragG[STG0 * 256 + i];
    __syncthreads();   // LDS stage 1 ready

    if (active) {
        // ---- stage 1, batch 0: offsets 14..20 ----
#pragma unroll
        for (int j = 0; j < BURST; ++j)
            A[j] = *(const bf16x8*)(fbase + (size_t)mi[STG0 + j] * C_IN);
#pragma unroll
        for (int j = 0; j < BURST; ++j) {
            const int k = j;
            bf16x8 b0 = lbase[k * 256 + 0 * 64];
            bf16x8 b1 = lbase[k * 256 + 1 * 64];
            bf16x8 b2 = lbase[k * 256 + 2 * 64];
            bf16x8 b3 = lbase[k * 256 + 3 * 64];
            acc0 = __builtin_amdgcn_mfma_f32_16x16x32_bf16(A[j], b0, acc0, 0, 0, 0);
            acc1 = __builtin_amdgcn_mfma_f32_16x16x32_bf16(A[j], b1, acc1, 0, 0, 0);
            acc2 = __builtin_amdgcn_mfma_f32_16x16x32_bf16(A[j], b2, acc2, 0, 0, 0);
            acc3 = __builtin_amdgcn_mfma_f32_16x16x32_bf16(A[j], b3, acc3, 0, 0, 0);
        }
        // ---- stage 1, batch 1: offsets 21..26 (6 iters) ----
#pragma unroll
        for (int j = 0; j < STG1 - BURST; ++j)
            A[j] = *(const bf16x8*)(fbase + (size_t)mi[STG0 + BURST + j] * C_IN);
#pragma unroll
        for (int j = 0; j < STG1 - BURST; ++j) {
            const int k = BURST + j;
            bf16x8 b0 = lbase[k * 256 + 0 * 64];
            bf16x8 b1 = lbase[k * 256 + 1 * 64];
            bf16x8 b2 = lbase[k * 256 + 2 * 64];
            bf16x8 b3 = lbase[k * 256 + 3 * 64];
            acc0 = __builtin_amdgcn_mfma_f32_16x16x32_bf16(A[j], b0, acc0, 0, 0, 0);
            acc1 = __builtin_amdgcn_mfma_f32_16x16x32_bf16(A[j], b1, acc1, 0, 0, 0);
            acc2 = __builtin_amdgcn_mfma_f32_16x16x32_bf16(A[j], b2, acc2, 0, 0, 0);
            acc3 = __builtin_amdgcn_mfma_f32_16x16x32_bf16(A[j], b3, acc3, 0, 0, 0);
        }

        float* op = out + (size_t)(m0 + quad * 4) * C_OUT + col;
#pragma unroll
        for (int r = 0; r < 4; ++r) {
            op[r * C_OUT + 0]  = acc0[r];
            op[r * C_OUT + 16] = acc1[r];
            op[r * C_OUT + 32] = acc2[r];
            op[r * C_OUT + 48] = acc3[r];
        }
    }
}

extern "C" void kernel_launch(void* const* d_in, const int* in_sizes, int n_in,
                              void* d_out, int out_size, void* d_ws, size_t ws_size,
                              hipStream_t stream) {
    const float* feats   = (const float*)d_in[0];
    const float* kernelw = (const float*)d_in[1];
    const int*   in_idx  = (const int*)d_in[2];
    const int*   maskp   = (const int*)d_in[3];
    float*       out     = (float*)d_out;

    __bf16* featsB = (__bf16*)d_ws;
    bf16x8* BfragP = (bf16x8*)((char*)d_ws + BFRAG_OFF);

    prep_all<<<dim3(FEAT_BLOCKS + K_VOL), dim3(256), 0, stream>>>(
        feats, kernelw, featsB, BfragP);

    const int blocks = (M_VOX + VOX_PER_BLK - 1) / VOX_PER_BLK;   // 782
    sparse_conv_mfma<<<dim3(blocks), dim3(BLK_THREADS), 0, stream>>>(
        featsB, BfragP, in_idx, maskp, out);
}